// Round 7
// baseline (379.639 us; speedup 1.0000x reference)
//
#include <hip/hip_runtime.h>
#include <hip/hip_bf16.h>
#include <math.h>

// MultiHeadDiffAttention, MI355X. Round 7: S^T trick — P^T lands in
// A-fragment layout directly (no P LDS round-trip), tile-paired K=32 PV,
// BKV=64 (16 iters, half the barriers). Epilogue/Oacc layout unchanged.
// B=2 S=2048 E=1024 H=8 DH=128 F=64.
// ws layout (64 MB):
//   [Oacc 32MB f32 (xb bf16 overlays head, dead before zero_ws)]
//   [wob 2MB][wqb 2MB <- Lacc overlays after gemm_qkv][wkb 2][wvb 2]
//   [Qb 8MB <- Nb overlays after attn][Kb 8MB][Vtb 8MB]

#define SDIM 2048
#define EDIM 1024
#define HDIM 8
#define DHDIM 128

typedef unsigned short u16;
typedef __attribute__((ext_vector_type(8))) short bf16x8;
typedef __attribute__((ext_vector_type(4))) short bf16x4;
typedef __attribute__((ext_vector_type(4))) u16 u16x4;
typedef __attribute__((ext_vector_type(8))) u16 u16x8;
typedef __attribute__((ext_vector_type(4))) float f32x4;

__device__ __forceinline__ u16 bf16rne(float f) {
    unsigned int u = __float_as_uint(f);
    u += 0x7fff + ((u >> 16) & 1);
    return (u16)(u >> 16);
}

__device__ __forceinline__ void gload16(void* lds, const void* g) {
    __builtin_amdgcn_global_load_lds(
        (const __attribute__((address_space(1))) unsigned int*)g,
        (__attribute__((address_space(3))) unsigned int*)lds, 16, 0, 0);
}

constexpr int GM = 4096, GN = 1024, GK = 1024;

// ------------------------------------------------------------------
// cast fp32 -> bf16: x (4M) + Wq/Wk/Wv/Wo (1M each).
// ------------------------------------------------------------------
__global__ __launch_bounds__(256) void cast_bf16(
    const float* __restrict__ x,  const float* __restrict__ wq,
    const float* __restrict__ wk, const float* __restrict__ wv,
    const float* __restrict__ wo,
    u16* __restrict__ xb,  u16* __restrict__ wqb, u16* __restrict__ wkb,
    u16* __restrict__ wvb, u16* __restrict__ wob)
{
    int bid = blockIdx.x;
    const float* src; u16* dst; int lb;
    if (bid < 2048)      { src = x;  dst = xb;  lb = bid; }
    else if (bid < 2560) { src = wq; dst = wqb; lb = bid - 2048; }
    else if (bid < 3072) { src = wk; dst = wkb; lb = bid - 2560; }
    else if (bid < 3584) { src = wv; dst = wvb; lb = bid - 3072; }
    else                 { src = wo; dst = wob; lb = bid - 3584; }
    size_t i = ((size_t)lb * 256 + threadIdx.x) * 8;
    float4 a = *(const float4*)&src[i];
    float4 b = *(const float4*)&src[i + 4];
    u16x8 o;
    o[0] = bf16rne(a.x); o[1] = bf16rne(a.y); o[2] = bf16rne(a.z); o[3] = bf16rne(a.w);
    o[4] = bf16rne(b.x); o[5] = bf16rne(b.y); o[6] = bf16rne(b.z); o[7] = bf16rne(b.w);
    *(u16x8*)&dst[i] = o;
}

// ------------------------------------------------------------------
// zero Oacc (8.39M f32) + Lacc (64K f32)
// ------------------------------------------------------------------
__global__ __launch_bounds__(256) void zero_ws(
    float* __restrict__ Oacc, float* __restrict__ Lacc)
{
    int bid = blockIdx.x;
    const f32x4 z = (f32x4){0.f, 0.f, 0.f, 0.f};
    if (bid < 8192) {
        *(f32x4*)&Oacc[((size_t)bid * 256 + threadIdx.x) * 4] = z;
    } else {
        *(f32x4*)&Lacc[((size_t)(bid - 8192) * 256 + threadIdx.x) * 4] = z;
    }
}

// ------------------------------------------------------------------
// bf16 MFMA GEMM core: C = A @ W^T, 128x128, BK=32. (unchanged)
// ------------------------------------------------------------------
struct GemmCore {
    f32x4 acc[4][4];
    int m0, n0, wm, wn, ln, quad;
};

__device__ __forceinline__ void gemm_core(
    GemmCore& g, const u16* __restrict__ A, const u16* __restrict__ W,
    u16* AsBase, u16* BsBase)
{
    const int tid = threadIdx.x;
    const int lane = tid & 63;
    const int wv = tid >> 6;
    g.ln = lane & 15; g.quad = lane >> 4;
    g.wm = (wv >> 1) * 64; g.wn = (wv & 1) * 64;
    g.m0 = blockIdx.y * 128; g.n0 = blockIdx.x * 128;

#pragma unroll
    for (int i = 0; i < 4; ++i)
#pragma unroll
        for (int j = 0; j < 4; ++j)
            g.acc[i][j] = (f32x4){0.f, 0.f, 0.f, 0.f};

    const int s0 = tid, s1 = tid + 256;
    const int ar0 = s0 >> 2, ac0 = (((s0 & 3) ^ ((ar0 >> 1) & 3)) * 8);
    const int ar1 = s1 >> 2, ac1 = (((s1 & 3) ^ ((ar1 >> 1) & 3)) * 8);
    const u16* pa0 = A + (size_t)(g.m0 + ar0) * GK + ac0;
    const u16* pa1 = A + (size_t)(g.m0 + ar1) * GK + ac1;
    const u16* pb0 = W + (size_t)(g.n0 + ar0) * GK + ac0;
    const u16* pb1 = W + (size_t)(g.n0 + ar1) * GK + ac1;
    u16* la0 = AsBase + s0 * 8; u16* la1 = AsBase + s1 * 8;
    u16* lb0 = BsBase + s0 * 8; u16* lb1 = BsBase + s1 * 8;

    const int roff = ((g.quad ^ ((g.ln >> 1) & 3)) * 8);

    for (int k0 = 0; k0 < GK; k0 += 32) {
        gload16(la0, pa0 + k0);
        gload16(la1, pa1 + k0);
        gload16(lb0, pb0 + k0);
        gload16(lb1, pb1 + k0);
        __syncthreads();

        bf16x8 af[4], bfr[4];
#pragma unroll
        for (int t = 0; t < 4; ++t) {
            af[t]  = *(const bf16x8*)&AsBase[(g.wm + t * 16 + g.ln) * 32 + roff];
            bfr[t] = *(const bf16x8*)&BsBase[(g.wn + t * 16 + g.ln) * 32 + roff];
        }
#pragma unroll
        for (int i = 0; i < 4; ++i)
#pragma unroll
            for (int j = 0; j < 4; ++j)
                g.acc[i][j] = __builtin_amdgcn_mfma_f32_16x16x32_bf16(
                    af[i], bfr[j], g.acc[i][j], 0, 0, 0);
        __syncthreads();
    }
}

// z=0 -> Qb (bf16, PRE-SCALED by 0.125*log2e), z=1 -> Kb, z=2 -> Vt
__global__ __launch_bounds__(256) void gemm_qkv(
    const u16* __restrict__ A,
    const u16* __restrict__ W0, const u16* __restrict__ W1, const u16* __restrict__ W2,
    u16* __restrict__ Qb, u16* __restrict__ Kb, u16* __restrict__ Vtb)
{
    __shared__ u16 As[128 * 32];
    __shared__ u16 Bs[128 * 32];
    const int z = blockIdx.z;
    const u16* W = (z == 0) ? W0 : ((z == 1) ? W1 : W2);
    GemmCore g;
    gemm_core(g, A, W, As, Bs);

    if (z < 2) {
        const float scl = (z == 0) ? 0.125f * 1.44269504f : 1.0f;
        u16* C = (z == 0) ? Qb : Kb;
#pragma unroll
        for (int i = 0; i < 4; ++i) {
            int rb = g.m0 + g.wm + i * 16 + g.quad * 4;
#pragma unroll
            for (int r = 0; r < 4; ++r) {
                u16* crow = C + (size_t)(rb + r) * GN + g.n0 + g.wn + g.ln;
#pragma unroll
                for (int j = 0; j < 4; ++j)
                    crow[j * 16] = bf16rne(g.acc[i][j][r] * scl);
            }
        }
    } else {
        const int bb = g.m0 >> 11;
        const int sb = (g.m0 & 2047) + g.wm + g.quad * 4;
#pragma unroll
        for (int j = 0; j < 4; ++j) {
            int dhg = g.n0 + g.wn + j * 16 + g.ln;
            int hh = dhg >> 7, dh = dhg & 127;
            u16* vrow = Vtb + ((size_t)(bb * 8 + hh) * DHDIM + dh) * SDIM + sb;
#pragma unroll
            for (int i = 0; i < 4; ++i) {
                u16x4 pk;
#pragma unroll
                for (int r = 0; r < 4; ++r) pk[r] = bf16rne(g.acc[i][j][r]);
                *(u16x4*)&vrow[i * 16] = pk;
            }
        }
    }
}

// out = (A @ W.T + bias) * (1-dw), fp32 output
__global__ __launch_bounds__(256) void gemm_out(
    const u16* __restrict__ A, const u16* __restrict__ W,
    float* __restrict__ C, const float* __restrict__ bias,
    const float* __restrict__ dwp)
{
    __shared__ u16 As[128 * 32];
    __shared__ u16 Bs[128 * 32];
    GemmCore g;
    gemm_core(g, A, W, As, Bs);

    const float scale = 1.0f - dwp[0];
    float bv[4];
#pragma unroll
    for (int j = 0; j < 4; ++j) bv[j] = bias[g.n0 + g.wn + j * 16 + g.ln];
#pragma unroll
    for (int i = 0; i < 4; ++i) {
        int rb = g.m0 + g.wm + i * 16 + g.quad * 4;
#pragma unroll
        for (int r = 0; r < 4; ++r) {
            float* crow = C + (size_t)(rb + r) * GN + g.n0 + g.wn + g.ln;
#pragma unroll
            for (int j = 0; j < 4; ++j)
                crow[j * 16] = (g.acc[i][j][r] + bv[j]) * scale;
        }
    }
}

// ------------------------------------------------------------------
// MFMA diff attention v5. Block = 4 waves, 64 q rows.
// Grid (32 qtiles, 16 bh, 2 kv-parts) = 1024 blocks. 16 iters of BKV=64.
// S^T = mfma(Kfrag, Qfrag): C-layout row=kv=quad*4+r, col=q=ln ->
// exp'd P^T is directly the PV A-fragment (lane owns q=ln). Adjacent
// 16-kv tiles pair into one K=32 PV MFMA (k=quad*8+{0..3|4..7}).
// V B-frags: two ds_read_b64 from swizzled Vs. No P LDS round-trip.
// acc C-layout identical to R6 -> epilogue/Oacc/rms unchanged.
// LDS: Ks 16KB (64 kv x 128 f, chunk^(row&7)) +
//      Vs 16KB (128 dh x 64 kv, chunk^(row&7)) = 32KB, 4 blocks/CU.
// ------------------------------------------------------------------
__global__ __launch_bounds__(256, 4) void attn_mfma(
    const u16* __restrict__ Qb, const u16* __restrict__ Kb,
    const u16* __restrict__ Vtb,
    float* __restrict__ Oacc, float* __restrict__ Lacc)
{
    __shared__ u16 Ks[64 * 128];
    __shared__ u16 Vs[128 * 64];

    const int tid = threadIdx.x;
    const int wv   = tid >> 6;
    const int lane = tid & 63;
    const int ln = lane & 15, quad = lane >> 4;
    const int l7 = ln & 7;
    const int q2 = quad >> 1, q1o = (quad & 1) * 4;
    const int bh = blockIdx.y, b = bh >> 3, h = bh & 7;
    const int q0 = blockIdx.x * 64 + wv * 16;
    const int kvbase = blockIdx.z * 1024;

    // Q fragments (pre-scaled by 0.125*log2e): [n=q=ln][k=feat=quad*8+j]
    const size_t qoff = (size_t)b * SDIM * EDIM + h * DHDIM;
    const u16* qp = Qb + qoff + (size_t)(q0 + ln) * EDIM + quad * 8;
    bf16x8 aq[2][2];
    aq[0][0] = *(const bf16x8*)(qp);
    aq[0][1] = *(const bf16x8*)(qp + 32);
    aq[1][0] = *(const bf16x8*)(qp + 64);
    aq[1][1] = *(const bf16x8*)(qp + 96);

    // staging maps (4 slots/thread per array)
    const u16 *kg[4], *vg[4]; u16 *ks[4], *vs[4];
#pragma unroll
    for (int u = 0; u < 4; ++u) {
        int s = tid + u * 256;
        int krow = s >> 4;
        int kgc = (s & 15) ^ (krow & 7);
        kg[u] = Kb + ((size_t)(b * SDIM + kvbase + krow)) * EDIM + h * DHDIM + kgc * 8;
        ks[u] = Ks + s * 8;
        int vrow = s >> 3;
        int vgc = (s & 7) ^ (vrow & 7);
        vg[u] = Vtb + ((size_t)bh * DHDIM + vrow) * SDIM + kvbase + vgc * 8;
        vs[u] = Vs + s * 8;
    }

    f32x4 acc0[8], acc1[8];
#pragma unroll
    for (int d = 0; d < 8; ++d) {
        acc0[d] = (f32x4){0.f, 0.f, 0.f, 0.f};
        acc1[d] = (f32x4){0.f, 0.f, 0.f, 0.f};
    }
    float lsum0 = 0.f, lsum1 = 0.f;
    const f32x4 z4 = (f32x4){0.f, 0.f, 0.f, 0.f};

    for (int it = 0; it < 16; ++it) {
        __syncthreads();                       // WAR on Ks/Vs
#pragma unroll
        for (int u = 0; u < 4; ++u) { gload16(ks[u], kg[u]); gload16(vs[u], vg[u]); }
#pragma unroll
        for (int u = 0; u < 4; ++u) { kg[u] += 64 * EDIM; vg[u] += 64; }
        __syncthreads();                       // staged data visible

#pragma unroll
        for (int tp = 0; tp < 2; ++tp) {       // tile pairs: kv [32tp, 32tp+32)
            // ---- QK^T (transposed): st[t2][br], rows=kv, cols=q ----
            f32x4 st[2][2];
#pragma unroll
            for (int t2 = 0; t2 < 2; ++t2) {
                const int row = (tp * 2 + t2) * 16 + ln;
#pragma unroll
                for (int br = 0; br < 2; ++br) {
                    bf16x8 k0 = *(const bf16x8*)&Ks[row * 128 + (((br * 8 + quad) ^ l7) * 8)];
                    bf16x8 k1 = *(const bf16x8*)&Ks[row * 128 + (((br * 8 + 4 + quad) ^ l7) * 8)];
                    f32x4 s = __builtin_amdgcn_mfma_f32_16x16x32_bf16(k0, aq[br][0], z4, 0, 0, 0);
                    st[t2][br] = __builtin_amdgcn_mfma_f32_16x16x32_bf16(k1, aq[br][1], s, 0, 0, 0);
                }
            }
            // ---- exp + lsum + pack P^T into A-frags (k=quad*8+j) ----
            union { unsigned int u[4]; bf16x8 v; } ap0, ap1;
            {
                float a0 = exp2f(st[0][0][0]), a1 = exp2f(st[0][0][1]);
                float a2 = exp2f(st[0][0][2]), a3 = exp2f(st[0][0][3]);
                float b0 = exp2f(st[1][0][0]), b1 = exp2f(st[1][0][1]);
                float b2 = exp2f(st[1][0][2]), b3 = exp2f(st[1][0][3]);
                lsum0 += (a0 + a1) + (a2 + a3) + (b0 + b1) + (b2 + b3);
                ap0.u[0] = __builtin_amdgcn_perm(__float_as_uint(a1), __float_as_uint(a0), 0x07060302u);
                ap0.u[1] = __builtin_amdgcn_perm(__float_as_uint(a3), __float_as_uint(a2), 0x07060302u);
                ap0.u[2] = __builtin_amdgcn_perm(__float_as_uint(b1), __float_as_uint(b0), 0x07060302u);
                ap0.u[3] = __builtin_amdgcn_perm(__float_as_uint(b3), __float_as_uint(b2), 0x07060302u);
            }
            {
                float a0 = exp2f(st[0][1][0]), a1 = exp2f(st[0][1][1]);
                float a2 = exp2f(st[0][1][2]), a3 = exp2f(st[0][1][3]);
                float b0 = exp2f(st[1][1][0]), b1 = exp2f(st[1][1][1]);
                float b2 = exp2f(st[1][1][2]), b3 = exp2f(st[1][1][3]);
                lsum1 += (a0 + a1) + (a2 + a3) + (b0 + b1) + (b2 + b3);
                ap1.u[0] = __builtin_amdgcn_perm(__float_as_uint(a1), __float_as_uint(a0), 0x07060302u);
                ap1.u[1] = __builtin_amdgcn_perm(__float_as_uint(a3), __float_as_uint(a2), 0x07060302u);
                ap1.u[2] = __builtin_amdgcn_perm(__float_as_uint(b1), __float_as_uint(b0), 0x07060302u);
                ap1.u[3] = __builtin_amdgcn_perm(__float_as_uint(b3), __float_as_uint(b2), 0x07060302u);
            }

            // ---- V B-frags (two b64 per dt) + PV ----
            const int c0 = (((tp * 2 + 0) * 2 + q2) ^ l7) * 8 + q1o;   // kv tile0 chunk
            const int c1 = (((tp * 2 + 1) * 2 + q2) ^ l7) * 8 + q1o;   // kv tile1 chunk
#pragma unroll
            for (int dt = 0; dt < 8; ++dt) {
                const int vbase = (dt * 16 + ln) * 64;
                bf16x4 vlo = *(const bf16x4*)&Vs[vbase + c0];
                bf16x4 vhi = *(const bf16x4*)&Vs[vbase + c1];
                bf16x8 vf = __builtin_shufflevector(vlo, vhi, 0, 1, 2, 3, 4, 5, 6, 7);
                acc0[dt] = __builtin_amdgcn_mfma_f32_16x16x32_bf16(ap0.v, vf, acc0[dt], 0, 0, 0);
                acc1[dt] = __builtin_amdgcn_mfma_f32_16x16x32_bf16(ap1.v, vf, acc1[dt], 0, 0, 0);
            }
        }
    }

    // ---- atomic accumulation of O partials (layout identical to R6) ----
#pragma unroll
    for (int r = 0; r < 4; ++r) {
        size_t row = (size_t)(b * SDIM + q0 + quad * 4 + r);
        float* o0 = Oacc + ((row * 8 + h) * 2 + 0) * 128 + ln;
        float* o1 = Oacc + ((row * 8 + h) * 2 + 1) * 128 + ln;
#pragma unroll
        for (int dt = 0; dt < 8; ++dt) {
            atomicAdd(o0 + dt * 16, acc0[dt][r]);
            atomicAdd(o1 + dt * 16, acc1[dt][r]);
        }
    }
    // ---- l: reduce across quads (lane owns q=ln), one atomic per q ----
    lsum0 += __shfl_xor(lsum0, 16, 64);
    lsum0 += __shfl_xor(lsum0, 32, 64);
    lsum1 += __shfl_xor(lsum1, 16, 64);
    lsum1 += __shfl_xor(lsum1, 32, 64);
    if (quad == 0) {
        atomicAdd(Lacc + (size_t)((b * 8 + h) * 2 + 0) * SDIM + q0 + ln, lsum0);
        atomicAdd(Lacc + (size_t)((b * 8 + h) * 2 + 1) * SDIM + q0 + ln, lsum1);
    }
}

// ------------------------------------------------------------------
// combine branches + RMSNorm -> bf16 normed. Grid 4096 rows x 256 thr.
// ------------------------------------------------------------------
__global__ __launch_bounds__(256) void rms_combine(
    const float* __restrict__ Oacc, const float* __restrict__ Lacc,
    const float* __restrict__ nw, u16* __restrict__ Nb,
    const float* __restrict__ dwp)
{
    const int row = blockIdx.x;
    const int tid = threadIdx.x;
    const int h = tid >> 5, dh0 = (tid & 31) * 4;
    const int b = row >> 11, q = row & 2047;

    size_t ob = ((size_t)row * 8 + h) * 2 * 128;
    f32x4 a0 = *(const f32x4*)&Oacc[ob + dh0];
    f32x4 a1 = *(const f32x4*)&Oacc[ob + 128 + dh0];
    float l0 = Lacc[(size_t)((b * 8 + h) * 2 + 0) * SDIM + q];
    float l1 = Lacc[(size_t)((b * 8 + h) * 2 + 1) * SDIM + q];
    const float dw = dwp[0];
    float inv0 = 1.0f / l0;
    float inv1 = dw / l1;
    float o[4];
#pragma unroll
    for (int k = 0; k < 4; ++k) o[k] = a0[k] * inv0 - a1[k] * inv1;

    float ss = o[0] * o[0] + o[1] * o[1] + o[2] * o[2] + o[3] * o[3];
    ss += __shfl_xor(ss, 1,  64);
    ss += __shfl_xor(ss, 2,  64);
    ss += __shfl_xor(ss, 4,  64);
    ss += __shfl_xor(ss, 8,  64);
    ss += __shfl_xor(ss, 16, 64);
    ss += __shfl_xor(ss, 32, 64);
    __shared__ float red[4];
    if ((tid & 63) == 0) red[tid >> 6] = ss;
    __syncthreads();
    float tot = red[0] + red[1] + red[2] + red[3];
    float rms = rsqrtf(tot * (1.0f / 1024.0f) + 1.1920929e-07f);

    float4 w = *(const float4*)&nw[tid * 4];
    u16x4 pk;
    pk[0] = bf16rne(o[0] * rms * w.x);
    pk[1] = bf16rne(o[1] * rms * w.y);
    pk[2] = bf16rne(o[2] * rms * w.z);
    pk[3] = bf16rne(o[3] * rms * w.w);
    *(u16x4*)&Nb[(size_t)row * EDIM + tid * 4] = pk;
}

// ------------------------------------------------------------------
extern "C" void kernel_launch(void* const* d_in, const int* in_sizes, int n_in,
                              void* d_out, int out_size, void* d_ws, size_t ws_size,
                              hipStream_t stream)
{
    const float* x   = (const float*)d_in[0];
    const float* Wq  = (const float*)d_in[1];
    const float* Wk  = (const float*)d_in[2];
    const float* Wv  = (const float*)d_in[3];
    const float* nw  = (const float*)d_in[4];
    const float* Wo  = (const float*)d_in[5];
    const float* bo  = (const float*)d_in[6];
    const float* dwp = (const float*)d_in[7];
    float* out = (float*)d_out;

    float* Oacc = (float*)d_ws;                          // 32 MB
    u16*  xb   = (u16*)d_ws;                             // overlays Oacc head
    u16*  wob  = (u16*)((char*)d_ws + 33554432);         // 2 MB
    u16*  wqb  = wob + 1048576;
    u16*  wkb  = wqb + 1048576;
    u16*  wvb  = wkb + 1048576;
    float* Lacc = (float*)wqb;                           // overlays wqb (dead)
    u16*  Qb   = wvb + 1048576;                          // 8 MB
    u16*  Kb   = Qb + 4194304;
    u16*  Vtb  = Kb + 4194304;
    u16*  Nb   = Qb;                                     // overlays Qb (dead)

    cast_bf16<<<4096, 256, 0, stream>>>(x, Wq, Wk, Wv, Wo,
                                        xb, wqb, wkb, wvb, wob);
    gemm_qkv<<<dim3(GN / 128, GM / 128, 3), 256, 0, stream>>>(
        xb, wqb, wkb, wvb, Qb, Kb, Vtb);
    zero_ws<<<8256, 256, 0, stream>>>(Oacc, Lacc);
    attn_mfma<<<dim3(SDIM / 64, 2 * HDIM, 2), 256, 0, stream>>>(
        Qb, Kb, Vtb, Oacc, Lacc);
    rms_combine<<<4096, 256, 0, stream>>>(Oacc, Lacc, nw, Nb, dwp);
    gemm_out<<<dim3(GN / 128, GM / 128, 1), 256, 0, stream>>>(
        Nb, wob, out, bo, dwp);
}

// Round 8
// 314.349 us; speedup vs baseline: 1.2077x; 1.2077x over previous
//
#include <hip/hip_runtime.h>
#include <hip/hip_bf16.h>
#include <math.h>

// MultiHeadDiffAttention, MI355X. Round 8: S^T in-register P (from R7)
// + R6's lean BKV=32 staging (scalar pointers, no spills) + double-buffered
// async global_load_lds with ONE barrier per iteration (loads for it+1 are
// in flight across the whole consume phase of it -> barrier drain ~free).
// B=2 S=2048 E=1024 H=8 DH=128 F=64.
// ws layout (64 MB):
//   [Oacc 32MB f32 (xb bf16 overlays head, dead before zero_ws)]
//   [wob 2MB][wqb 2MB <- Lacc overlays after gemm_qkv][wkb 2][wvb 2]
//   [Qb 8MB <- Nb overlays after attn][Kb 8MB][Vtb 8MB]

#define SDIM 2048
#define EDIM 1024
#define HDIM 8
#define DHDIM 128

typedef unsigned short u16;
typedef __attribute__((ext_vector_type(8))) short bf16x8;
typedef __attribute__((ext_vector_type(4))) short bf16x4;
typedef __attribute__((ext_vector_type(4))) u16 u16x4;
typedef __attribute__((ext_vector_type(8))) u16 u16x8;
typedef __attribute__((ext_vector_type(4))) float f32x4;

__device__ __forceinline__ u16 bf16rne(float f) {
    unsigned int u = __float_as_uint(f);
    u += 0x7fff + ((u >> 16) & 1);
    return (u16)(u >> 16);
}

__device__ __forceinline__ void gload16(void* lds, const void* g) {
    __builtin_amdgcn_global_load_lds(
        (const __attribute__((address_space(1))) unsigned int*)g,
        (__attribute__((address_space(3))) unsigned int*)lds, 16, 0, 0);
}

constexpr int GM = 4096, GN = 1024, GK = 1024;

// ------------------------------------------------------------------
// cast fp32 -> bf16: x (4M) + Wq/Wk/Wv/Wo (1M each).
// ------------------------------------------------------------------
__global__ __launch_bounds__(256) void cast_bf16(
    const float* __restrict__ x,  const float* __restrict__ wq,
    const float* __restrict__ wk, const float* __restrict__ wv,
    const float* __restrict__ wo,
    u16* __restrict__ xb,  u16* __restrict__ wqb, u16* __restrict__ wkb,
    u16* __restrict__ wvb, u16* __restrict__ wob)
{
    int bid = blockIdx.x;
    const float* src; u16* dst; int lb;
    if (bid < 2048)      { src = x;  dst = xb;  lb = bid; }
    else if (bid < 2560) { src = wq; dst = wqb; lb = bid - 2048; }
    else if (bid < 3072) { src = wk; dst = wkb; lb = bid - 2560; }
    else if (bid < 3584) { src = wv; dst = wvb; lb = bid - 3072; }
    else                 { src = wo; dst = wob; lb = bid - 3584; }
    size_t i = ((size_t)lb * 256 + threadIdx.x) * 8;
    float4 a = *(const float4*)&src[i];
    float4 b = *(const float4*)&src[i + 4];
    u16x8 o;
    o[0] = bf16rne(a.x); o[1] = bf16rne(a.y); o[2] = bf16rne(a.z); o[3] = bf16rne(a.w);
    o[4] = bf16rne(b.x); o[5] = bf16rne(b.y); o[6] = bf16rne(b.z); o[7] = bf16rne(b.w);
    *(u16x8*)&dst[i] = o;
}

// ------------------------------------------------------------------
// zero Oacc (8.39M f32) + Lacc (64K f32)
// ------------------------------------------------------------------
__global__ __launch_bounds__(256) void zero_ws(
    float* __restrict__ Oacc, float* __restrict__ Lacc)
{
    int bid = blockIdx.x;
    const f32x4 z = (f32x4){0.f, 0.f, 0.f, 0.f};
    if (bid < 8192) {
        *(f32x4*)&Oacc[((size_t)bid * 256 + threadIdx.x) * 4] = z;
    } else {
        *(f32x4*)&Lacc[((size_t)(bid - 8192) * 256 + threadIdx.x) * 4] = z;
    }
}

// ------------------------------------------------------------------
// bf16 MFMA GEMM core: C = A @ W^T, 128x128, BK=32. (unchanged)
// ------------------------------------------------------------------
struct GemmCore {
    f32x4 acc[4][4];
    int m0, n0, wm, wn, ln, quad;
};

__device__ __forceinline__ void gemm_core(
    GemmCore& g, const u16* __restrict__ A, const u16* __restrict__ W,
    u16* AsBase, u16* BsBase)
{
    const int tid = threadIdx.x;
    const int lane = tid & 63;
    const int wv = tid >> 6;
    g.ln = lane & 15; g.quad = lane >> 4;
    g.wm = (wv >> 1) * 64; g.wn = (wv & 1) * 64;
    g.m0 = blockIdx.y * 128; g.n0 = blockIdx.x * 128;

#pragma unroll
    for (int i = 0; i < 4; ++i)
#pragma unroll
        for (int j = 0; j < 4; ++j)
            g.acc[i][j] = (f32x4){0.f, 0.f, 0.f, 0.f};

    const int s0 = tid, s1 = tid + 256;
    const int ar0 = s0 >> 2, ac0 = (((s0 & 3) ^ ((ar0 >> 1) & 3)) * 8);
    const int ar1 = s1 >> 2, ac1 = (((s1 & 3) ^ ((ar1 >> 1) & 3)) * 8);
    const u16* pa0 = A + (size_t)(g.m0 + ar0) * GK + ac0;
    const u16* pa1 = A + (size_t)(g.m0 + ar1) * GK + ac1;
    const u16* pb0 = W + (size_t)(g.n0 + ar0) * GK + ac0;
    const u16* pb1 = W + (size_t)(g.n0 + ar1) * GK + ac1;
    u16* la0 = AsBase + s0 * 8; u16* la1 = AsBase + s1 * 8;
    u16* lb0 = BsBase + s0 * 8; u16* lb1 = BsBase + s1 * 8;

    const int roff = ((g.quad ^ ((g.ln >> 1) & 3)) * 8);

    for (int k0 = 0; k0 < GK; k0 += 32) {
        gload16(la0, pa0 + k0);
        gload16(la1, pa1 + k0);
        gload16(lb0, pb0 + k0);
        gload16(lb1, pb1 + k0);
        __syncthreads();

        bf16x8 af[4], bfr[4];
#pragma unroll
        for (int t = 0; t < 4; ++t) {
            af[t]  = *(const bf16x8*)&AsBase[(g.wm + t * 16 + g.ln) * 32 + roff];
            bfr[t] = *(const bf16x8*)&BsBase[(g.wn + t * 16 + g.ln) * 32 + roff];
        }
#pragma unroll
        for (int i = 0; i < 4; ++i)
#pragma unroll
            for (int j = 0; j < 4; ++j)
                g.acc[i][j] = __builtin_amdgcn_mfma_f32_16x16x32_bf16(
                    af[i], bfr[j], g.acc[i][j], 0, 0, 0);
        __syncthreads();
    }
}

// z=0 -> Qb (bf16, PRE-SCALED by 0.125*log2e), z=1 -> Kb, z=2 -> Vt
__global__ __launch_bounds__(256) void gemm_qkv(
    const u16* __restrict__ A,
    const u16* __restrict__ W0, const u16* __restrict__ W1, const u16* __restrict__ W2,
    u16* __restrict__ Qb, u16* __restrict__ Kb, u16* __restrict__ Vtb)
{
    __shared__ u16 As[128 * 32];
    __shared__ u16 Bs[128 * 32];
    const int z = blockIdx.z;
    const u16* W = (z == 0) ? W0 : ((z == 1) ? W1 : W2);
    GemmCore g;
    gemm_core(g, A, W, As, Bs);

    if (z < 2) {
        const float scl = (z == 0) ? 0.125f * 1.44269504f : 1.0f;
        u16* C = (z == 0) ? Qb : Kb;
#pragma unroll
        for (int i = 0; i < 4; ++i) {
            int rb = g.m0 + g.wm + i * 16 + g.quad * 4;
#pragma unroll
            for (int r = 0; r < 4; ++r) {
                u16* crow = C + (size_t)(rb + r) * GN + g.n0 + g.wn + g.ln;
#pragma unroll
                for (int j = 0; j < 4; ++j)
                    crow[j * 16] = bf16rne(g.acc[i][j][r] * scl);
            }
        }
    } else {
        const int bb = g.m0 >> 11;
        const int sb = (g.m0 & 2047) + g.wm + g.quad * 4;
#pragma unroll
        for (int j = 0; j < 4; ++j) {
            int dhg = g.n0 + g.wn + j * 16 + g.ln;
            int hh = dhg >> 7, dh = dhg & 127;
            u16* vrow = Vtb + ((size_t)(bb * 8 + hh) * DHDIM + dh) * SDIM + sb;
#pragma unroll
            for (int i = 0; i < 4; ++i) {
                u16x4 pk;
#pragma unroll
                for (int r = 0; r < 4; ++r) pk[r] = bf16rne(g.acc[i][j][r]);
                *(u16x4*)&vrow[i * 16] = pk;
            }
        }
    }
}

// out = (A @ W.T + bias) * (1-dw), fp32 output
__global__ __launch_bounds__(256) void gemm_out(
    const u16* __restrict__ A, const u16* __restrict__ W,
    float* __restrict__ C, const float* __restrict__ bias,
    const float* __restrict__ dwp)
{
    __shared__ u16 As[128 * 32];
    __shared__ u16 Bs[128 * 32];
    GemmCore g;
    gemm_core(g, A, W, As, Bs);

    const float scale = 1.0f - dwp[0];
    float bv[4];
#pragma unroll
    for (int j = 0; j < 4; ++j) bv[j] = bias[g.n0 + g.wn + j * 16 + g.ln];
#pragma unroll
    for (int i = 0; i < 4; ++i) {
        int rb = g.m0 + g.wm + i * 16 + g.quad * 4;
#pragma unroll
        for (int r = 0; r < 4; ++r) {
            float* crow = C + (size_t)(rb + r) * GN + g.n0 + g.wn + g.ln;
#pragma unroll
            for (int j = 0; j < 4; ++j)
                crow[j * 16] = (g.acc[i][j][r] + bv[j]) * scale;
        }
    }
}

// ------------------------------------------------------------------
// MFMA diff attention v6. Block = 4 waves, 64 q rows.
// Grid (32 qtiles, 16 bh, 2 kv-parts) = 1024 blocks. 32 iters of BKV=32.
// Double-buffered K/V staging (2 x 8KB each), ONE barrier per iter:
//   barrier -> issue gloads for it+1 into buf^1 -> consume buf.
// S^T = mfma(Kfrag, Qfrag): lane (ln,quad) holds S^T[kv=quad*4+r][q=ln]
// -> exp'd P^T packs in-register into the PV A-fragment (k=quad*8+j,
// kv(j<4)=quad*4+j, kv(j>=4)=16+quad*4+j-4). V B-frag: two b64 reads
// matching the same kv mapping. acc C-layout = R6 epilogue (unchanged).
// ------------------------------------------------------------------
__global__ __launch_bounds__(256, 3) void attn_mfma(
    const u16* __restrict__ Qb, const u16* __restrict__ Kb,
    const u16* __restrict__ Vtb,
    float* __restrict__ Oacc, float* __restrict__ Lacc)
{
    __shared__ u16 Ks[2 * 32 * 128];   // dbuf: 32 kv x 128 f per buffer
    __shared__ u16 Vs[2 * 128 * 32];   // dbuf: 128 dh x 32 kv per buffer

    const int tid = threadIdx.x;
    const int wv   = tid >> 6;
    const int lane = tid & 63;
    const int ln = lane & 15, quad = lane >> 4;
    const int lx = ln & 7;
    const int vkey = (ln >> 1) & 3;
    const int bh = blockIdx.y, b = bh >> 3, h = bh & 7;
    const int q0 = blockIdx.x * 64 + wv * 16;
    const int kvbase = blockIdx.z * 1024;

    // Q fragments (pre-scaled): feats br*64 + half*32 + quad*8
    const size_t qoff = (size_t)b * SDIM * EDIM + h * DHDIM;
    const u16* qp = Qb + qoff + (size_t)(q0 + ln) * EDIM + quad * 8;
    bf16x8 aq[2][2];
    aq[0][0] = *(const bf16x8*)(qp);
    aq[0][1] = *(const bf16x8*)(qp + 32);
    aq[1][0] = *(const bf16x8*)(qp + 64);
    aq[1][1] = *(const bf16x8*)(qp + 96);

    // staging maps (R6-proven): K row s>>4, chunk (s&15)^(row&7);
    //                           V row s>>2, chunk (s&3)^((row>>1)&3)
    const int s0 = tid, s1 = tid + 256;
    const int kr0 = s0 >> 4, kc0 = ((s0 & 15) ^ (kr0 & 7)) * 8;
    const int kr1 = s1 >> 4, kc1 = ((s1 & 15) ^ (kr1 & 7)) * 8;
    const u16* kg0 = Kb + (size_t)(b * SDIM + kvbase + kr0) * EDIM + h * DHDIM + kc0;
    const u16* kg1 = Kb + (size_t)(b * SDIM + kvbase + kr1) * EDIM + h * DHDIM + kc1;
    const int vr0 = s0 >> 2, vc0 = ((s0 & 3) ^ ((vr0 >> 1) & 3)) * 8;
    const int vr1 = s1 >> 2, vc1 = ((s1 & 3) ^ ((vr1 >> 1) & 3)) * 8;
    const u16* vg0 = Vtb + ((size_t)bh * DHDIM + vr0) * SDIM + kvbase + vc0;
    const u16* vg1 = Vtb + ((size_t)bh * DHDIM + vr1) * SDIM + kvbase + vc1;
    u16* ks0 = Ks + s0 * 8; u16* ks1 = Ks + s1 * 8;
    u16* vs0 = Vs + s0 * 8; u16* vs1 = Vs + s1 * 8;

    // prologue: stage iter 0 into buffer 0
    gload16(ks0, kg0); gload16(ks1, kg1);
    gload16(vs0, vg0); gload16(vs1, vg1);
    kg0 += 32 * EDIM; kg1 += 32 * EDIM; vg0 += 32; vg1 += 32;

    f32x4 acc0[8], acc1[8];
#pragma unroll
    for (int d = 0; d < 8; ++d) {
        acc0[d] = (f32x4){0.f, 0.f, 0.f, 0.f};
        acc1[d] = (f32x4){0.f, 0.f, 0.f, 0.f};
    }
    float lsum0 = 0.f, lsum1 = 0.f;
    const f32x4 z4 = (f32x4){0.f, 0.f, 0.f, 0.f};

    for (int it = 0; it < 32; ++it) {
        const int cur = it & 1;
        __syncthreads();   // buf[cur] loads complete; all waves done reading buf[cur^1]

        if (it < 31) {     // prefetch iter it+1 into the other buffer
            const int nb = (cur ^ 1) * 4096;
            gload16(ks0 + nb, kg0); gload16(ks1 + nb, kg1);
            gload16(vs0 + nb, vg0); gload16(vs1 + nb, vg1);
            kg0 += 32 * EDIM; kg1 += 32 * EDIM; vg0 += 32; vg1 += 32;
        }

        const u16* Kc = Ks + cur * 4096;
        const u16* Vc = Vs + cur * 4096;

        // ---- S^T = K(A) x Q(B): st[t2][br], lane holds kv=quad*4+r, q=ln ----
        f32x4 st[2][2];
#pragma unroll
        for (int t2 = 0; t2 < 2; ++t2) {
            const int rb = (t2 * 16 + ln) * 128;
#pragma unroll
            for (int br = 0; br < 2; ++br) {
                bf16x8 k0 = *(const bf16x8*)&Kc[rb + (((br * 8 + quad) ^ lx) * 8)];
                bf16x8 k1 = *(const bf16x8*)&Kc[rb + (((br * 8 + 4 + quad) ^ lx) * 8)];
                f32x4 s = __builtin_amdgcn_mfma_f32_16x16x32_bf16(k0, aq[br][0], z4, 0, 0, 0);
                st[t2][br] = __builtin_amdgcn_mfma_f32_16x16x32_bf16(k1, aq[br][1], s, 0, 0, 0);
            }
        }

        // ---- exp + lsum + in-register pack into PV A-frags ----
        union { unsigned int u[4]; bf16x8 v; } ap0, ap1;
        {
            float e0 = exp2f(st[0][0][0]), e1 = exp2f(st[0][0][1]);
            float e2 = exp2f(st[0][0][2]), e3 = exp2f(st[0][0][3]);
            float f0 = exp2f(st[1][0][0]), f1 = exp2f(st[1][0][1]);
            float f2 = exp2f(st[1][0][2]), f3 = exp2f(st[1][0][3]);
            lsum0 += (e0 + e1) + (e2 + e3) + (f0 + f1) + (f2 + f3);
            ap0.u[0] = __builtin_amdgcn_perm(__float_as_uint(e1), __float_as_uint(e0), 0x07060302u);
            ap0.u[1] = __builtin_amdgcn_perm(__float_as_uint(e3), __float_as_uint(e2), 0x07060302u);
            ap0.u[2] = __builtin_amdgcn_perm(__float_as_uint(f1), __float_as_uint(f0), 0x07060302u);
            ap0.u[3] = __builtin_amdgcn_perm(__float_as_uint(f3), __float_as_uint(f2), 0x07060302u);
        }
        {
            float e0 = exp2f(st[0][1][0]), e1 = exp2f(st[0][1][1]);
            float e2 = exp2f(st[0][1][2]), e3 = exp2f(st[0][1][3]);
            float f0 = exp2f(st[1][1][0]), f1 = exp2f(st[1][1][1]);
            float f2 = exp2f(st[1][1][2]), f3 = exp2f(st[1][1][3]);
            lsum1 += (e0 + e1) + (e2 + e3) + (f0 + f1) + (f2 + f3);
            ap1.u[0] = __builtin_amdgcn_perm(__float_as_uint(e1), __float_as_uint(e0), 0x07060302u);
            ap1.u[1] = __builtin_amdgcn_perm(__float_as_uint(e3), __float_as_uint(e2), 0x07060302u);
            ap1.u[2] = __builtin_amdgcn_perm(__float_as_uint(f1), __float_as_uint(f0), 0x07060302u);
            ap1.u[3] = __builtin_amdgcn_perm(__float_as_uint(f3), __float_as_uint(f2), 0x07060302u);
        }

        // ---- PV: V B-frag needs kv(j<4)=quad*4+j, kv(j>=4)=16+quad*4+j-4 ----
#pragma unroll
        for (int dt = 0; dt < 8; ++dt) {
            const int vb = (dt * 16 + ln) * 32;
            bf16x4 vlo = *(const bf16x4*)&Vc[vb + ((((quad >> 1) + 0) ^ vkey) * 8 + (quad & 1) * 4)];
            bf16x4 vhi = *(const bf16x4*)&Vc[vb + ((((quad >> 1) + 2) ^ vkey) * 8 + (quad & 1) * 4)];
            bf16x8 vf = __builtin_shufflevector(vlo, vhi, 0, 1, 2, 3, 4, 5, 6, 7);
            acc0[dt] = __builtin_amdgcn_mfma_f32_16x16x32_bf16(ap0.v, vf, acc0[dt], 0, 0, 0);
            acc1[dt] = __builtin_amdgcn_mfma_f32_16x16x32_bf16(ap1.v, vf, acc1[dt], 0, 0, 0);
        }
    }

    // ---- atomic accumulation of O partials (layout = R6 epilogue) ----
#pragma unroll
    for (int r = 0; r < 4; ++r) {
        size_t row = (size_t)(b * SDIM + q0 + quad * 4 + r);
        float* o0 = Oacc + ((row * 8 + h) * 2 + 0) * 128 + ln;
        float* o1 = Oacc + ((row * 8 + h) * 2 + 1) * 128 + ln;
#pragma unroll
        for (int dt = 0; dt < 8; ++dt) {
            atomicAdd(o0 + dt * 16, acc0[dt][r]);
            atomicAdd(o1 + dt * 16, acc1[dt][r]);
        }
    }
    // ---- l: lane owns q=ln; reduce across quads, one atomic per q ----
    lsum0 += __shfl_xor(lsum0, 16, 64);
    lsum0 += __shfl_xor(lsum0, 32, 64);
    lsum1 += __shfl_xor(lsum1, 16, 64);
    lsum1 += __shfl_xor(lsum1, 32, 64);
    if (quad == 0) {
        atomicAdd(Lacc + (size_t)((b * 8 + h) * 2 + 0) * SDIM + q0 + ln, lsum0);
        atomicAdd(Lacc + (size_t)((b * 8 + h) * 2 + 1) * SDIM + q0 + ln, lsum1);
    }
}

// ------------------------------------------------------------------
// combine branches + RMSNorm -> bf16 normed. Grid 4096 rows x 256 thr.
// ------------------------------------------------------------------
__global__ __launch_bounds__(256) void rms_combine(
    const float* __restrict__ Oacc, const float* __restrict__ Lacc,
    const float* __restrict__ nw, u16* __restrict__ Nb,
    const float* __restrict__ dwp)
{
    const int row = blockIdx.x;
    const int tid = threadIdx.x;
    const int h = tid >> 5, dh0 = (tid & 31) * 4;
    const int b = row >> 11, q = row & 2047;

    size_t ob = ((size_t)row * 8 + h) * 2 * 128;
    f32x4 a0 = *(const f32x4*)&Oacc[ob + dh0];
    f32x4 a1 = *(const f32x4*)&Oacc[ob + 128 + dh0];
    float l0 = Lacc[(size_t)((b * 8 + h) * 2 + 0) * SDIM + q];
    float l1 = Lacc[(size_t)((b * 8 + h) * 2 + 1) * SDIM + q];
    const float dw = dwp[0];
    float inv0 = 1.0f / l0;
    float inv1 = dw / l1;
    float o[4];
#pragma unroll
    for (int k = 0; k < 4; ++k) o[k] = a0[k] * inv0 - a1[k] * inv1;

    float ss = o[0] * o[0] + o[1] * o[1] + o[2] * o[2] + o[3] * o[3];
    ss += __shfl_xor(ss, 1,  64);
    ss += __shfl_xor(ss, 2,  64);
    ss += __shfl_xor(ss, 4,  64);
    ss += __shfl_xor(ss, 8,  64);
    ss += __shfl_xor(ss, 16, 64);
    ss += __shfl_xor(ss, 32, 64);
    __shared__ float red[4];
    if ((tid & 63) == 0) red[tid >> 6] = ss;
    __syncthreads();
    float tot = red[0] + red[1] + red[2] + red[3];
    float rms = rsqrtf(tot * (1.0f / 1024.0f) + 1.1920929e-07f);

    float4 w = *(const float4*)&nw[tid * 4];
    u16x4 pk;
    pk[0] = bf16rne(o[0] * rms * w.x);
    pk[1] = bf16rne(o[1] * rms * w.y);
    pk[2] = bf16rne(o[2] * rms * w.z);
    pk[3] = bf16rne(o[3] * rms * w.w);
    *(u16x4*)&Nb[(size_t)row * EDIM + tid * 4] = pk;
}

// ------------------------------------------------------------------
extern "C" void kernel_launch(void* const* d_in, const int* in_sizes, int n_in,
                              void* d_out, int out_size, void* d_ws, size_t ws_size,
                              hipStream_t stream)
{
    const float* x   = (const float*)d_in[0];
    const float* Wq  = (const float*)d_in[1];
    const float* Wk  = (const float*)d_in[2];
    const float* Wv  = (const float*)d_in[3];
    const float* nw  = (const float*)d_in[4];
    const float* Wo  = (const float*)d_in[5];
    const float* bo  = (const float*)d_in[6];
    const float* dwp = (const float*)d_in[7];
    float* out = (float*)d_out;

    float* Oacc = (float*)d_ws;                          // 32 MB
    u16*  xb   = (u16*)d_ws;                             // overlays Oacc head
    u16*  wob  = (u16*)((char*)d_ws + 33554432);         // 2 MB
    u16*  wqb  = wob + 1048576;
    u16*  wkb  = wqb + 1048576;
    u16*  wvb  = wkb + 1048576;
    float* Lacc = (float*)wqb;                           // overlays wqb (dead)
    u16*  Qb   = wvb + 1048576;                          // 8 MB
    u16*  Kb   = Qb + 4194304;
    u16*  Vtb  = Kb + 4194304;
    u16*  Nb   = Qb;                                     // overlays Qb (dead)

    cast_bf16<<<4096, 256, 0, stream>>>(x, Wq, Wk, Wv, Wo,
                                        xb, wqb, wkb, wvb, wob);
    gemm_qkv<<<dim3(GN / 128, GM / 128, 3), 256, 0, stream>>>(
        xb, wqb, wkb, wvb, Qb, Kb, Vtb);
    zero_ws<<<8256, 256, 0, stream>>>(Oacc, Lacc);
    attn_mfma<<<dim3(SDIM / 64, 2 * HDIM, 2), 256, 0, stream>>>(
        Qb, Kb, Vtb, Oacc, Lacc);
    rms_combine<<<4096, 256, 0, stream>>>(Oacc, Lacc, nw, Nb, dwp);
    gemm_out<<<dim3(GN / 128, GM / 128, 1), 256, 0, stream>>>(
        Nb, wob, out, bo, dwp);
}

// Round 9
// 294.982 us; speedup vs baseline: 1.2870x; 1.0657x over previous
//
#include <hip/hip_runtime.h>
#include <hip/hip_bf16.h>
#include <math.h>

// MultiHeadDiffAttention, MI355X. Round 9: 32 q-rows per wave (2 q-tiles).
// S^T scheme shares K(A-op) and V(B-op) fragments across q-tiles ->
// LDS reads/iter constant while MFMA doubles; 2 independent dep chains
// per wave. Grid 512 = 2 blocks/CU co-resident, zero tail.
// Keeps: dbuf 1-barrier global_load_lds staging, in-register P pack,
// additive no-max softmax partials, fused combine+RMSNorm.
// B=2 S=2048 E=1024 H=8 DH=128 F=64.
// ws layout (64 MB):
//   [Oacc 32MB f32 (xb bf16 overlays head, dead before zero_ws)]
//   [wob 2MB][wqb 2MB <- Lacc overlays after gemm_qkv][wkb 2][wvb 2]
//   [Qb 8MB <- Nb overlays after attn][Kb 8MB][Vtb 8MB]

#define SDIM 2048
#define EDIM 1024
#define HDIM 8
#define DHDIM 128

typedef unsigned short u16;
typedef __attribute__((ext_vector_type(8))) short bf16x8;
typedef __attribute__((ext_vector_type(4))) short bf16x4;
typedef __attribute__((ext_vector_type(4))) u16 u16x4;
typedef __attribute__((ext_vector_type(8))) u16 u16x8;
typedef __attribute__((ext_vector_type(4))) float f32x4;

__device__ __forceinline__ u16 bf16rne(float f) {
    unsigned int u = __float_as_uint(f);
    u += 0x7fff + ((u >> 16) & 1);
    return (u16)(u >> 16);
}

__device__ __forceinline__ void gload16(void* lds, const void* g) {
    __builtin_amdgcn_global_load_lds(
        (const __attribute__((address_space(1))) unsigned int*)g,
        (__attribute__((address_space(3))) unsigned int*)lds, 16, 0, 0);
}

constexpr int GM = 4096, GN = 1024, GK = 1024;

// ------------------------------------------------------------------
// cast fp32 -> bf16: x (4M) + Wq/Wk/Wv/Wo (1M each).
// ------------------------------------------------------------------
__global__ __launch_bounds__(256) void cast_bf16(
    const float* __restrict__ x,  const float* __restrict__ wq,
    const float* __restrict__ wk, const float* __restrict__ wv,
    const float* __restrict__ wo,
    u16* __restrict__ xb,  u16* __restrict__ wqb, u16* __restrict__ wkb,
    u16* __restrict__ wvb, u16* __restrict__ wob)
{
    int bid = blockIdx.x;
    const float* src; u16* dst; int lb;
    if (bid < 2048)      { src = x;  dst = xb;  lb = bid; }
    else if (bid < 2560) { src = wq; dst = wqb; lb = bid - 2048; }
    else if (bid < 3072) { src = wk; dst = wkb; lb = bid - 2560; }
    else if (bid < 3584) { src = wv; dst = wvb; lb = bid - 3072; }
    else                 { src = wo; dst = wob; lb = bid - 3584; }
    size_t i = ((size_t)lb * 256 + threadIdx.x) * 8;
    float4 a = *(const float4*)&src[i];
    float4 b = *(const float4*)&src[i + 4];
    u16x8 o;
    o[0] = bf16rne(a.x); o[1] = bf16rne(a.y); o[2] = bf16rne(a.z); o[3] = bf16rne(a.w);
    o[4] = bf16rne(b.x); o[5] = bf16rne(b.y); o[6] = bf16rne(b.z); o[7] = bf16rne(b.w);
    *(u16x8*)&dst[i] = o;
}

// ------------------------------------------------------------------
// zero Oacc (8.39M f32) + Lacc (64K f32)
// ------------------------------------------------------------------
__global__ __launch_bounds__(256) void zero_ws(
    float* __restrict__ Oacc, float* __restrict__ Lacc)
{
    int bid = blockIdx.x;
    const f32x4 z = (f32x4){0.f, 0.f, 0.f, 0.f};
    if (bid < 8192) {
        *(f32x4*)&Oacc[((size_t)bid * 256 + threadIdx.x) * 4] = z;
    } else {
        *(f32x4*)&Lacc[((size_t)(bid - 8192) * 256 + threadIdx.x) * 4] = z;
    }
}

// ------------------------------------------------------------------
// bf16 MFMA GEMM core: C = A @ W^T, 128x128, BK=32. (unchanged)
// ------------------------------------------------------------------
struct GemmCore {
    f32x4 acc[4][4];
    int m0, n0, wm, wn, ln, quad;
};

__device__ __forceinline__ void gemm_core(
    GemmCore& g, const u16* __restrict__ A, const u16* __restrict__ W,
    u16* AsBase, u16* BsBase)
{
    const int tid = threadIdx.x;
    const int lane = tid & 63;
    const int wv = tid >> 6;
    g.ln = lane & 15; g.quad = lane >> 4;
    g.wm = (wv >> 1) * 64; g.wn = (wv & 1) * 64;
    g.m0 = blockIdx.y * 128; g.n0 = blockIdx.x * 128;

#pragma unroll
    for (int i = 0; i < 4; ++i)
#pragma unroll
        for (int j = 0; j < 4; ++j)
            g.acc[i][j] = (f32x4){0.f, 0.f, 0.f, 0.f};

    const int s0 = tid, s1 = tid + 256;
    const int ar0 = s0 >> 2, ac0 = (((s0 & 3) ^ ((ar0 >> 1) & 3)) * 8);
    const int ar1 = s1 >> 2, ac1 = (((s1 & 3) ^ ((ar1 >> 1) & 3)) * 8);
    const u16* pa0 = A + (size_t)(g.m0 + ar0) * GK + ac0;
    const u16* pa1 = A + (size_t)(g.m0 + ar1) * GK + ac1;
    const u16* pb0 = W + (size_t)(g.n0 + ar0) * GK + ac0;
    const u16* pb1 = W + (size_t)(g.n0 + ar1) * GK + ac1;
    u16* la0 = AsBase + s0 * 8; u16* la1 = AsBase + s1 * 8;
    u16* lb0 = BsBase + s0 * 8; u16* lb1 = BsBase + s1 * 8;

    const int roff = ((g.quad ^ ((g.ln >> 1) & 3)) * 8);

    for (int k0 = 0; k0 < GK; k0 += 32) {
        gload16(la0, pa0 + k0);
        gload16(la1, pa1 + k0);
        gload16(lb0, pb0 + k0);
        gload16(lb1, pb1 + k0);
        __syncthreads();

        bf16x8 af[4], bfr[4];
#pragma unroll
        for (int t = 0; t < 4; ++t) {
            af[t]  = *(const bf16x8*)&AsBase[(g.wm + t * 16 + g.ln) * 32 + roff];
            bfr[t] = *(const bf16x8*)&BsBase[(g.wn + t * 16 + g.ln) * 32 + roff];
        }
#pragma unroll
        for (int i = 0; i < 4; ++i)
#pragma unroll
            for (int j = 0; j < 4; ++j)
                g.acc[i][j] = __builtin_amdgcn_mfma_f32_16x16x32_bf16(
                    af[i], bfr[j], g.acc[i][j], 0, 0, 0);
        __syncthreads();
    }
}

// z=0 -> Qb (bf16, PRE-SCALED by 0.125*log2e), z=1 -> Kb, z=2 -> Vt
__global__ __launch_bounds__(256) void gemm_qkv(
    const u16* __restrict__ A,
    const u16* __restrict__ W0, const u16* __restrict__ W1, const u16* __restrict__ W2,
    u16* __restrict__ Qb, u16* __restrict__ Kb, u16* __restrict__ Vtb)
{
    __shared__ u16 As[128 * 32];
    __shared__ u16 Bs[128 * 32];
    const int z = blockIdx.z;
    const u16* W = (z == 0) ? W0 : ((z == 1) ? W1 : W2);
    GemmCore g;
    gemm_core(g, A, W, As, Bs);

    if (z < 2) {
        const float scl = (z == 0) ? 0.125f * 1.44269504f : 1.0f;
        u16* C = (z == 0) ? Qb : Kb;
#pragma unroll
        for (int i = 0; i < 4; ++i) {
            int rb = g.m0 + g.wm + i * 16 + g.quad * 4;
#pragma unroll
            for (int r = 0; r < 4; ++r) {
                u16* crow = C + (size_t)(rb + r) * GN + g.n0 + g.wn + g.ln;
#pragma unroll
                for (int j = 0; j < 4; ++j)
                    crow[j * 16] = bf16rne(g.acc[i][j][r] * scl);
            }
        }
    } else {
        const int bb = g.m0 >> 11;
        const int sb = (g.m0 & 2047) + g.wm + g.quad * 4;
#pragma unroll
        for (int j = 0; j < 4; ++j) {
            int dhg = g.n0 + g.wn + j * 16 + g.ln;
            int hh = dhg >> 7, dh = dhg & 127;
            u16* vrow = Vtb + ((size_t)(bb * 8 + hh) * DHDIM + dh) * SDIM + sb;
#pragma unroll
            for (int i = 0; i < 4; ++i) {
                u16x4 pk;
#pragma unroll
                for (int r = 0; r < 4; ++r) pk[r] = bf16rne(g.acc[i][j][r]);
                *(u16x4*)&vrow[i * 16] = pk;
            }
        }
    }
}

// out = (A @ W.T + bias) * (1-dw), fp32 output
__global__ __launch_bounds__(256) void gemm_out(
    const u16* __restrict__ A, const u16* __restrict__ W,
    float* __restrict__ C, const float* __restrict__ bias,
    const float* __restrict__ dwp)
{
    __shared__ u16 As[128 * 32];
    __shared__ u16 Bs[128 * 32];
    GemmCore g;
    gemm_core(g, A, W, As, Bs);

    const float scale = 1.0f - dwp[0];
    float bv[4];
#pragma unroll
    for (int j = 0; j < 4; ++j) bv[j] = bias[g.n0 + g.wn + j * 16 + g.ln];
#pragma unroll
    for (int i = 0; i < 4; ++i) {
        int rb = g.m0 + g.wm + i * 16 + g.quad * 4;
#pragma unroll
        for (int r = 0; r < 4; ++r) {
            float* crow = C + (size_t)(rb + r) * GN + g.n0 + g.wn + g.ln;
#pragma unroll
            for (int j = 0; j < 4; ++j)
                crow[j * 16] = (g.acc[i][j][r] + bv[j]) * scale;
        }
    }
}

// ------------------------------------------------------------------
// MFMA diff attention v7. Block = 4 waves; wave owns 32 q (2 q-tiles).
// Grid (16 qtiles, 16 bh, 2 kv-parts) = 512 blocks = 2/CU, zero tail.
// 32 iters of BKV=32, dbuf 1-barrier staging.
// S^T = mfma(K_A, Q_B): K/V fragments shared across both q-tiles ->
// LDS reads constant, MFMA 2x, two independent dep chains per wave.
// ------------------------------------------------------------------
__global__ __launch_bounds__(256, 2) void attn_mfma(
    const u16* __restrict__ Qb, const u16* __restrict__ Kb,
    const u16* __restrict__ Vtb,
    float* __restrict__ Oacc, float* __restrict__ Lacc)
{
    __shared__ u16 Ks[2 * 32 * 128];   // dbuf: 32 kv x 128 f per buffer
    __shared__ u16 Vs[2 * 128 * 32];   // dbuf: 128 dh x 32 kv per buffer

    const int tid = threadIdx.x;
    const int wv   = tid >> 6;
    const int lane = tid & 63;
    const int ln = lane & 15, quad = lane >> 4;
    const int lx = ln & 7;
    const int vkey = (ln >> 1) & 3;
    const int bh = blockIdx.y, b = bh >> 3, h = bh & 7;
    const int q0 = blockIdx.x * 128 + wv * 32;        // wave's 32 q rows
    const int kvbase = blockIdx.z * 1024;

    // Q B-frags (pre-scaled): [qt][br][half], feats br*64 + half*32 + quad*8
    const size_t qoff = (size_t)b * SDIM * EDIM + h * DHDIM;
    bf16x8 aq[2][2][2];
#pragma unroll
    for (int qt = 0; qt < 2; ++qt) {
        const u16* qp = Qb + qoff + (size_t)(q0 + qt * 16 + ln) * EDIM + quad * 8;
        aq[qt][0][0] = *(const bf16x8*)(qp);
        aq[qt][0][1] = *(const bf16x8*)(qp + 32);
        aq[qt][1][0] = *(const bf16x8*)(qp + 64);
        aq[qt][1][1] = *(const bf16x8*)(qp + 96);
    }

    // staging maps: K row s>>4, chunk (s&15)^(row&7);
    //               V row s>>2, chunk (s&3)^((row>>1)&3)
    const int s0 = tid, s1 = tid + 256;
    const int kr0 = s0 >> 4, kc0 = ((s0 & 15) ^ (kr0 & 7)) * 8;
    const int kr1 = s1 >> 4, kc1 = ((s1 & 15) ^ (kr1 & 7)) * 8;
    const u16* kg0 = Kb + (size_t)(b * SDIM + kvbase + kr0) * EDIM + h * DHDIM + kc0;
    const u16* kg1 = Kb + (size_t)(b * SDIM + kvbase + kr1) * EDIM + h * DHDIM + kc1;
    const int vr0 = s0 >> 2, vc0 = ((s0 & 3) ^ ((vr0 >> 1) & 3)) * 8;
    const int vr1 = s1 >> 2, vc1 = ((s1 & 3) ^ ((vr1 >> 1) & 3)) * 8;
    const u16* vg0 = Vtb + ((size_t)bh * DHDIM + vr0) * SDIM + kvbase + vc0;
    const u16* vg1 = Vtb + ((size_t)bh * DHDIM + vr1) * SDIM + kvbase + vc1;
    u16* ks0 = Ks + s0 * 8; u16* ks1 = Ks + s1 * 8;
    u16* vs0 = Vs + s0 * 8; u16* vs1 = Vs + s1 * 8;

    // prologue: stage iter 0 into buffer 0
    gload16(ks0, kg0); gload16(ks1, kg1);
    gload16(vs0, vg0); gload16(vs1, vg1);
    kg0 += 32 * EDIM; kg1 += 32 * EDIM; vg0 += 32; vg1 += 32;

    f32x4 acc[2][2][8];                 // [qt][br][dt]
#pragma unroll
    for (int qt = 0; qt < 2; ++qt)
#pragma unroll
        for (int br = 0; br < 2; ++br)
#pragma unroll
            for (int d = 0; d < 8; ++d)
                acc[qt][br][d] = (f32x4){0.f, 0.f, 0.f, 0.f};
    float lsum[2][2] = {{0.f, 0.f}, {0.f, 0.f}};
    const f32x4 z4 = (f32x4){0.f, 0.f, 0.f, 0.f};

    for (int it = 0; it < 32; ++it) {
        const int cur = it & 1;
        __syncthreads();   // buf[cur] loads complete; all waves done with buf[cur^1]

        if (it < 31) {     // prefetch iter it+1 into the other buffer
            const int nb = (cur ^ 1) * 4096;
            gload16(ks0 + nb, kg0); gload16(ks1 + nb, kg1);
            gload16(vs0 + nb, vg0); gload16(vs1 + nb, vg1);
            kg0 += 32 * EDIM; kg1 += 32 * EDIM; vg0 += 32; vg1 += 32;
        }

        const u16* Kc = Ks + cur * 4096;
        const u16* Vc = Vs + cur * 4096;

        // ---- S^T: st[qt][t2][br]; K frags shared across qt ----
        f32x4 st[2][2][2];
#pragma unroll
        for (int t2 = 0; t2 < 2; ++t2) {
            const int rb = (t2 * 16 + ln) * 128;
#pragma unroll
            for (int br = 0; br < 2; ++br) {
                bf16x8 k0 = *(const bf16x8*)&Kc[rb + (((br * 8 + quad) ^ lx) * 8)];
                bf16x8 k1 = *(const bf16x8*)&Kc[rb + (((br * 8 + 4 + quad) ^ lx) * 8)];
#pragma unroll
                for (int qt = 0; qt < 2; ++qt) {
                    f32x4 s = __builtin_amdgcn_mfma_f32_16x16x32_bf16(k0, aq[qt][br][0], z4, 0, 0, 0);
                    st[qt][t2][br] = __builtin_amdgcn_mfma_f32_16x16x32_bf16(k1, aq[qt][br][1], s, 0, 0, 0);
                }
            }
        }

        // ---- exp + lsum + in-register pack into PV A-frags ----
        union { unsigned int u[4]; bf16x8 v; } ap[2][2];
#pragma unroll
        for (int qt = 0; qt < 2; ++qt)
#pragma unroll
            for (int br = 0; br < 2; ++br) {
                float e0 = exp2f(st[qt][0][br][0]), e1 = exp2f(st[qt][0][br][1]);
                float e2 = exp2f(st[qt][0][br][2]), e3 = exp2f(st[qt][0][br][3]);
                float f0 = exp2f(st[qt][1][br][0]), f1 = exp2f(st[qt][1][br][1]);
                float f2 = exp2f(st[qt][1][br][2]), f3 = exp2f(st[qt][1][br][3]);
                lsum[qt][br] += (e0 + e1) + (e2 + e3) + (f0 + f1) + (f2 + f3);
                ap[qt][br].u[0] = __builtin_amdgcn_perm(__float_as_uint(e1), __float_as_uint(e0), 0x07060302u);
                ap[qt][br].u[1] = __builtin_amdgcn_perm(__float_as_uint(e3), __float_as_uint(e2), 0x07060302u);
                ap[qt][br].u[2] = __builtin_amdgcn_perm(__float_as_uint(f1), __float_as_uint(f0), 0x07060302u);
                ap[qt][br].u[3] = __builtin_amdgcn_perm(__float_as_uint(f3), __float_as_uint(f2), 0x07060302u);
            }

        // ---- PV: V B-frag shared across qt & br (4 MFMAs per read) ----
#pragma unroll
        for (int dt = 0; dt < 8; ++dt) {
            const int vb = (dt * 16 + ln) * 32;
            bf16x4 vlo = *(const bf16x4*)&Vc[vb + ((((quad >> 1) + 0) ^ vkey) * 8 + (quad & 1) * 4)];
            bf16x4 vhi = *(const bf16x4*)&Vc[vb + ((((quad >> 1) + 2) ^ vkey) * 8 + (quad & 1) * 4)];
            bf16x8 vf = __builtin_shufflevector(vlo, vhi, 0, 1, 2, 3, 4, 5, 6, 7);
#pragma unroll
            for (int qt = 0; qt < 2; ++qt) {
                acc[qt][0][dt] = __builtin_amdgcn_mfma_f32_16x16x32_bf16(ap[qt][0].v, vf, acc[qt][0][dt], 0, 0, 0);
                acc[qt][1][dt] = __builtin_amdgcn_mfma_f32_16x16x32_bf16(ap[qt][1].v, vf, acc[qt][1][dt], 0, 0, 0);
            }
        }
    }

    // ---- atomic accumulation of O partials (row layout = R6 epilogue) ----
#pragma unroll
    for (int qt = 0; qt < 2; ++qt) {
#pragma unroll
        for (int r = 0; r < 4; ++r) {
            size_t row = (size_t)(b * SDIM + q0 + qt * 16 + quad * 4 + r);
            float* o0 = Oacc + ((row * 8 + h) * 2 + 0) * 128 + ln;
            float* o1 = Oacc + ((row * 8 + h) * 2 + 1) * 128 + ln;
#pragma unroll
            for (int dt = 0; dt < 8; ++dt) {
                atomicAdd(o0 + dt * 16, acc[qt][0][dt][r]);
                atomicAdd(o1 + dt * 16, acc[qt][1][dt][r]);
            }
        }
    }
    // ---- l: lane owns q=ln within tile; reduce across quads ----
#pragma unroll
    for (int qt = 0; qt < 2; ++qt) {
        float l0 = lsum[qt][0], l1 = lsum[qt][1];
        l0 += __shfl_xor(l0, 16, 64); l0 += __shfl_xor(l0, 32, 64);
        l1 += __shfl_xor(l1, 16, 64); l1 += __shfl_xor(l1, 32, 64);
        if (quad == 0) {
            atomicAdd(Lacc + (size_t)((b * 8 + h) * 2 + 0) * SDIM + q0 + qt * 16 + ln, l0);
            atomicAdd(Lacc + (size_t)((b * 8 + h) * 2 + 1) * SDIM + q0 + qt * 16 + ln, l1);
        }
    }
}

// ------------------------------------------------------------------
// combine branches + RMSNorm -> bf16 normed. Grid 4096 rows x 256 thr.
// ------------------------------------------------------------------
__global__ __launch_bounds__(256) void rms_combine(
    const float* __restrict__ Oacc, const float* __restrict__ Lacc,
    const float* __restrict__ nw, u16* __restrict__ Nb,
    const float* __restrict__ dwp)
{
    const int row = blockIdx.x;
    const int tid = threadIdx.x;
    const int h = tid >> 5, dh0 = (tid & 31) * 4;
    const int b = row >> 11, q = row & 2047;

    size_t ob = ((size_t)row * 8 + h) * 2 * 128;
    f32x4 a0 = *(const f32x4*)&Oacc[ob + dh0];
    f32x4 a1 = *(const f32x4*)&Oacc[ob + 128 + dh0];
    float l0 = Lacc[(size_t)((b * 8 + h) * 2 + 0) * SDIM + q];
    float l1 = Lacc[(size_t)((b * 8 + h) * 2 + 1) * SDIM + q];
    const float dw = dwp[0];
    float inv0 = 1.0f / l0;
    float inv1 = dw / l1;
    float o[4];
#pragma unroll
    for (int k = 0; k < 4; ++k) o[k] = a0[k] * inv0 - a1[k] * inv1;

    float ss = o[0] * o[0] + o[1] * o[1] + o[2] * o[2] + o[3] * o[3];
    ss += __shfl_xor(ss, 1,  64);
    ss += __shfl_xor(ss, 2,  64);
    ss += __shfl_xor(ss, 4,  64);
    ss += __shfl_xor(ss, 8,  64);
    ss += __shfl_xor(ss, 16, 64);
    ss += __shfl_xor(ss, 32, 64);
    __shared__ float red[4];
    if ((tid & 63) == 0) red[tid >> 6] = ss;
    __syncthreads();
    float tot = red[0] + red[1] + red[2] + red[3];
    float rms = rsqrtf(tot * (1.0f / 1024.0f) + 1.1920929e-07f);

    float4 w = *(const float4*)&nw[tid * 4];
    u16x4 pk;
    pk[0] = bf16rne(o[0] * rms * w.x);
    pk[1] = bf16rne(o[1] * rms * w.y);
    pk[2] = bf16rne(o[2] * rms * w.z);
    pk[3] = bf16rne(o[3] * rms * w.w);
    *(u16x4*)&Nb[(size_t)row * EDIM + tid * 4] = pk;
}

// ------------------------------------------------------------------
extern "C" void kernel_launch(void* const* d_in, const int* in_sizes, int n_in,
                              void* d_out, int out_size, void* d_ws, size_t ws_size,
                              hipStream_t stream)
{
    const float* x   = (const float*)d_in[0];
    const float* Wq  = (const float*)d_in[1];
    const float* Wk  = (const float*)d_in[2];
    const float* Wv  = (const float*)d_in[3];
    const float* nw  = (const float*)d_in[4];
    const float* Wo  = (const float*)d_in[5];
    const float* bo  = (const float*)d_in[6];
    const float* dwp = (const float*)d_in[7];
    float* out = (float*)d_out;

    float* Oacc = (float*)d_ws;                          // 32 MB
    u16*  xb   = (u16*)d_ws;                             // overlays Oacc head
    u16*  wob  = (u16*)((char*)d_ws + 33554432);         // 2 MB
    u16*  wqb  = wob + 1048576;
    u16*  wkb  = wqb + 1048576;
    u16*  wvb  = wkb + 1048576;
    float* Lacc = (float*)wqb;                           // overlays wqb (dead)
    u16*  Qb   = wvb + 1048576;                          // 8 MB
    u16*  Kb   = Qb + 4194304;
    u16*  Vtb  = Kb + 4194304;
    u16*  Nb   = Qb;                                     // overlays Qb (dead)

    cast_bf16<<<4096, 256, 0, stream>>>(x, Wq, Wk, Wv, Wo,
                                        xb, wqb, wkb, wvb, wob);
    gemm_qkv<<<dim3(GN / 128, GM / 128, 3), 256, 0, stream>>>(
        xb, wqb, wkb, wvb, Qb, Kb, Vtb);
    zero_ws<<<8256, 256, 0, stream>>>(Oacc, Lacc);
    attn_mfma<<<dim3(SDIM / 128, 2 * HDIM, 2), 256, 0, stream>>>(
        Qb, Kb, Vtb, Oacc, Lacc);
    rms_combine<<<4096, 256, 0, stream>>>(Oacc, Lacc, nw, Nb, dwp);
    gemm_out<<<dim3(GN / 128, GM / 128, 1), 256, 0, stream>>>(
        Nb, wob, out, bo, dwp);
}